// Round 10
// baseline (207.630 us; speedup 1.0000x reference)
//
#include <hip/hip_runtime.h>
#include <hip/hip_bf16.h>

#define Bsz 4
#define Ssz 1024
#define Dsz 768
#define Hn 12
#define DKsz 64
#define NUMEMB 10

// d_ws layout (bytes)
#define IDX_OFF 64
#define K_OFF   4194368          // IDX_OFF + 4*1024*1024
#define V_OFF   10485824         // K_OFF + 4*1024*768*2
#define WBF_OFF 16777280         // V_OFF + 4*1024*768*2
#define XBF_OFF 20316224         // WBF_OFF + 3*768*768*2
#define WS_TIER_B 20316224ULL    // enough for Wbf
#define WS_TIER_A 39190592ULL    // enough for Wbf + Xbf

#define NXz 3145728              // elems per X tensor (4*1024*768)
#define NWz 589824               // elems per W tensor (768*768)

// attn LDS: double-buffered unpadded [64][64], XOR chunk swizzle
#define KVBUF 4096               // shorts per buffer (64*64)
#define QBLK 128                 // q rows per block (8 waves x 16)

typedef __attribute__((ext_vector_type(8))) short short8;
typedef __attribute__((ext_vector_type(8))) float float8;
typedef __attribute__((ext_vector_type(4))) float f32x4;
typedef __attribute__((ext_vector_type(4))) unsigned int u32x4;
typedef __attribute__((ext_vector_type(2))) unsigned int u32x2;
typedef __attribute__((ext_vector_type(4))) short s16x4;

__device__ __forceinline__ float bfbits2f(short u) {
    union { unsigned int i; float f; } v;
    v.i = ((unsigned int)(unsigned short)u) << 16;
    return v.f;
}
__device__ __forceinline__ unsigned short f2bf_bits(float f) {
    __hip_bfloat16 h = __float2bfloat16(f);
    return *reinterpret_cast<unsigned short*>(&h);
}

// wave-local dtype vote. Returns 1 = bf16, 0 = f32. Uniform per wave.
__device__ __forceinline__ int dtvote(const unsigned int* p, int n) {
    int cnt = 0;
    for (int i = (threadIdx.x & 63); i < n; i += 64) {
        const unsigned int ex = (p[i] >> 7) & 0xFF;
        cnt += (ex >= 110 && ex <= 145) ? 1 : 0;
    }
#pragma unroll
    for (int off = 1; off < 64; off <<= 1) cnt += __shfl_xor(cnt, off, 64);
    return (2 * cnt > n) ? 1 : 0;
}

// dtype-dispatched loads: idx is an ELEMENT index
template<bool BF16>
__device__ __forceinline__ float loadf(const void* base, size_t idx) {
    if constexpr (BF16) return __bfloat162float(((const __hip_bfloat16*)base)[idx]);
    else return ((const float*)base)[idx];
}
template<bool BF16>
__device__ __forceinline__ short8 load8bf(const void* base, size_t idx) {
    if constexpr (BF16) {
        return *(const short8*)((const short*)base + idx);
    } else {
        float8 f = *(const float8*)((const float*)base + idx);
        short8 r;
#pragma unroll
        for (int i = 0; i < 8; i++) r[i] = (short)f2bf_bits(f[i]);
        return r;
    }
}
template<bool BF16>
__device__ __forceinline__ float8 load8f(const void* base, size_t idx) {
    if constexpr (BF16) {
        short8 s = *(const short8*)((const short*)base + idx);
        float8 f;
#pragma unroll
        for (int i = 0; i < 8; i++) f[i] = bfbits2f(s[i]);
        return f;
    } else {
        return *(const float8*)((const float*)base + idx);
    }
}

// ---------------- idx tile body (shared by idx_kernel and prep_kernel) -----
// Exact fp32 op chain matching numpy; matrix is bitwise symmetric.
template<bool PB>
__device__ __forceinline__ void idx_body(
    const void* pos, unsigned char* __restrict__ idxb, int kt, int qt, int b)
{
    const int t = threadIdx.x;
    const int r = t >> 2, cc = t & 3;
    const int q = qt * 64 + r;
    const float qx = loadf<PB>(pos, ((size_t)b * Ssz + q) * 2);
    const float qy = loadf<PB>(pos, ((size_t)b * Ssz + q) * 2 + 1);
    const float MAXD = 141421.35623730951f;  // fp32(100000*sqrt(2))
    const int k0 = kt * 64 + cc * 16;
    unsigned int w[4];
#pragma unroll
    for (int g = 0; g < 4; g++) {
        unsigned int acc = 0;
#pragma unroll
        for (int u = 0; u < 4; u++) {
            const int k = k0 + g * 4 + u;
            const float kx = loadf<PB>(pos, ((size_t)b * Ssz + k) * 2);
            const float ky = loadf<PB>(pos, ((size_t)b * Ssz + k) * 2 + 1);
            const float dx = __fsub_rn(qx, kx);
            const float dy = __fsub_rn(qy, ky);
            const float ss = __fadd_rn(__fmul_rn(dx, dx), __fmul_rn(dy, dy));
            const float dist = __fdiv_rn(sqrtf(ss), MAXD);
            const float d9 = __fmul_rn(dist, 9.0f);
            int idx = (int)rintf(d9);
            idx = idx < 0 ? 0 : (idx > NUMEMB - 1 ? NUMEMB - 1 : idx);
            acc |= ((unsigned int)idx) << (8 * u);
        }
        w[g] = acc;
    }
    u32x4 v; v[0] = w[0]; v[1] = w[1]; v[2] = w[2]; v[3] = w[3];
    *(u32x4*)(idxb + ((size_t)(b * Ssz + q)) * Ssz + k0) = v;
}

// ---------------- dtype detector (tierC only) ------------------------------
__global__ __launch_bounds__(64) void detect_kernel(
    const unsigned int* __restrict__ q, const unsigned int* __restrict__ p,
    const unsigned int* __restrict__ w, const unsigned int* __restrict__ e,
    int* __restrict__ flags)
{
    const int which = blockIdx.x;
    const unsigned int* ptr = (which == 0) ? q : ((which == 1) ? p : ((which == 2) ? w : e));
    const int n = (which == 3) ? 320 : ((which == 1) ? 4096 : 1024);
    const int f = dtvote(ptr, n);
    if (threadIdx.x == 0) flags[which] = f;
}

__global__ __launch_bounds__(256) void idx_kernel(
    const void* pos, const int* __restrict__ flags, unsigned char* __restrict__ idxb)
{
    if (flags[1] != 0) idx_body<true >(pos, idxb, blockIdx.x, blockIdx.y, blockIdx.z);
    else               idx_body<false>(pos, idxb, blockIdx.x, blockIdx.y, blockIdx.z);
}

// ---------------- prep: fused conv + idx + flag duty (tierA/B) -------------
// Blocks [0, nconv): bf16 canonicalization of X/W (local dtype votes,
// blocks 0-3 also publish flags for downstream proj/attn).
// Blocks [nconv, nconv+1024): idx tiles (local tpos vote).
__global__ __launch_bounds__(256) void prep_kernel(
    const void* __restrict__ X0, const void* __restrict__ X1, const void* __restrict__ X2,
    const void* __restrict__ W0, const void* __restrict__ W1, const void* __restrict__ W2,
    const void* __restrict__ tpos, const void* __restrict__ emb,
    int* __restrict__ flags, short* __restrict__ Xbf, short* __restrict__ Wbf,
    unsigned char* __restrict__ idxb, int nconv, int doX)
{
    if ((int)blockIdx.x >= nconv) {
        const int i = blockIdx.x - nconv;          // 0..1023
        const int kt = i & 15, qt = (i >> 4) & 15, b = i >> 8;
        const int pb = dtvote((const unsigned int*)tpos, 1024);
        if (pb) idx_body<true >(tpos, idxb, kt, qt, b);
        else    idx_body<false>(tpos, idxb, kt, qt, b);
        return;
    }

    // flag duty for downstream kernels (proj/attn read flags)
    if (blockIdx.x == 1) {
        const int f = dtvote((const unsigned int*)tpos, 1024);
        if (threadIdx.x == 0) flags[1] = f;
    } else if (blockIdx.x == 3) {
        const int f = dtvote((const unsigned int*)emb, 320);
        if (threadIdx.x == 0) flags[3] = f;
    }
    const bool xb = dtvote((const unsigned int*)X0, 256) != 0;
    const bool wb = dtvote((const unsigned int*)W0, 256) != 0;
    if (blockIdx.x == 0 && threadIdx.x == 0) { flags[0] = xb ? 1 : 0; flags[2] = wb ? 1 : 0; }

    const long t = (long)blockIdx.x * 256 + threadIdx.x;
    if (doX) {
        const long i8 = t * 8;
        if (i8 < (long)3 * NXz) {
            const int z = (int)(i8 / NXz);
            const long off = i8 - (long)z * NXz;
            const void* X = (z == 0) ? X0 : ((z == 1) ? X1 : X2);
            short8 v = xb ? load8bf<true>(X, off) : load8bf<false>(X, off);
            *(short8*)(Xbf + i8) = v;
        } else {
            const long j = i8 - (long)3 * NXz;
            const int z = (int)(j / NWz);
            const long off = j - (long)z * NWz;
            const void* W = (z == 0) ? W0 : ((z == 1) ? W1 : W2);
            short8 v = wb ? load8bf<true>(W, off) : load8bf<false>(W, off);
            *(short8*)(Wbf + j) = v;
        }
    } else {
        const long j = t * 8;
        const int z = (int)(j / NWz);
        const long off = j - (long)z * NWz;
        const void* W = (z == 0) ? W0 : ((z == 1) ? W1 : W2);
        short8 v = wb ? load8bf<true>(W, off) : load8bf<false>(W, off);
        *(short8*)(Wbf + j) = v;
    }
}

// ---------------- Projection GEMM: Y = X @ W^T + b (reg-staged, 64x128) ----
// zmode: 0 = Q plain [m][768]; 1 = K [b][h][s][dk] bf16; 2 = V^T [b][h][dk][s] bf16.
template<bool XB, bool WB>
__device__ __forceinline__ void proj_body(
    const void* X, const void* W, const void* bias, bool biasbf, void* Y, bool ybf,
    int zmode, int bx, int by, short* As, short* Bs)
{
    const int tid  = threadIdx.x;
    const int wave = tid >> 6;
    const int lane = tid & 63;
    const int l15  = lane & 15;
    const int quad = lane >> 4;
    const int wm = wave & 1;
    const int wn = wave >> 1;
    const int m0 = bx * 64;
    const int n0 = by * 128;

    f32x4 acc[2][4];
#pragma unroll
    for (int i = 0; i < 2; i++)
#pragma unroll
        for (int j = 0; j < 4; j++) acc[i][j] = (f32x4)0.0f;

    const int r0 = tid >> 3;     // staging row 0..31
    const int cc = tid & 7;      // staging col-chunk (8 elems)

    short8 pa0 = load8bf<XB>(X, (size_t)(m0 + r0)      * Dsz + cc * 8);
    short8 pa1 = load8bf<XB>(X, (size_t)(m0 + 32 + r0) * Dsz + cc * 8);
    short8 pb0 = load8bf<WB>(W, (size_t)(n0 + r0)      * Dsz + cc * 8);
    short8 pb1 = load8bf<WB>(W, (size_t)(n0 + 32 + r0) * Dsz + cc * 8);
    short8 pb2 = load8bf<WB>(W, (size_t)(n0 + 64 + r0) * Dsz + cc * 8);
    short8 pb3 = load8bf<WB>(W, (size_t)(n0 + 96 + r0) * Dsz + cc * 8);

    for (int kk = 0; kk < Dsz; kk += 64) {
        __syncthreads();
        *(short8*)&As[(r0)      * 72 + cc * 8] = pa0;
        *(short8*)&As[(32 + r0) * 72 + cc * 8] = pa1;
        *(short8*)&Bs[(r0)      * 72 + cc * 8] = pb0;
        *(short8*)&Bs[(32 + r0) * 72 + cc * 8] = pb1;
        *(short8*)&Bs[(64 + r0) * 72 + cc * 8] = pb2;
        *(short8*)&Bs[(96 + r0) * 72 + cc * 8] = pb3;
        __syncthreads();

        if (kk + 64 < Dsz) {
            const int k2 = kk + 64 + cc * 8;
            pa0 = load8bf<XB>(X, (size_t)(m0 + r0)      * Dsz + k2);
            pa1 = load8bf<XB>(X, (size_t)(m0 + 32 + r0) * Dsz + k2);
            pb0 = load8bf<WB>(W, (size_t)(n0 + r0)      * Dsz + k2);
            pb1 = load8bf<WB>(W, (size_t)(n0 + 32 + r0) * Dsz + k2);
            pb2 = load8bf<WB>(W, (size_t)(n0 + 64 + r0) * Dsz + k2);
            pb3 = load8bf<WB>(W, (size_t)(n0 + 96 + r0) * Dsz + k2);
        }

#pragma unroll
        for (int st = 0; st < 2; st++) {
            short8 af[2], bf[4];
#pragma unroll
            for (int i = 0; i < 2; i++)
                af[i] = *(const short8*)&As[(wm * 32 + i * 16 + l15) * 72 + st * 32 + quad * 8];
#pragma unroll
            for (int j = 0; j < 4; j++)
                bf[j] = *(const short8*)&Bs[(wn * 64 + j * 16 + l15) * 72 + st * 32 + quad * 8];
#pragma unroll
            for (int i = 0; i < 2; i++)
#pragma unroll
                for (int j = 0; j < 4; j++)
                    acc[i][j] = __builtin_amdgcn_mfma_f32_16x16x32_bf16(af[i], bf[j], acc[i][j], 0, 0, 0);
        }
    }

#pragma unroll
    for (int j = 0; j < 4; j++) {
        const int n = n0 + wn * 64 + j * 16 + l15;
        const float bv_ = biasbf ? loadf<true>(bias, n) : loadf<false>(bias, n);
        const int hh = n >> 6, dk = n & 63;
#pragma unroll
        for (int i = 0; i < 2; i++) {
            const int ms = m0 + wm * 32 + i * 16 + quad * 4;   // 4 consecutive rows
            const int bb = ms >> 10;
            const int s0 = ms & 1023;
            if (zmode == 2) {
                s16x4 pkv;
#pragma unroll
                for (int r = 0; r < 4; r++) pkv[r] = (short)f2bf_bits(acc[i][j][r] + bv_);
                *(s16x4*)((short*)Y + (((size_t)bb * Hn + hh) * DKsz + dk) * Ssz + s0) = pkv;
            } else if (zmode == 1) {
#pragma unroll
                for (int r = 0; r < 4; r++)
                    ((__hip_bfloat16*)Y)[(((size_t)bb * Hn + hh) * Ssz + (s0 + r)) * DKsz + dk] =
                        __float2bfloat16(acc[i][j][r] + bv_);
            } else {
#pragma unroll
                for (int r = 0; r < 4; r++) {
                    const float val = acc[i][j][r] + bv_;
                    const size_t oi = (size_t)(ms + r) * Dsz + n;
                    if (ybf) ((__hip_bfloat16*)Y)[oi] = __float2bfloat16(val);
                    else     ((float*)Y)[oi] = val;
                }
            }
        }
    }
}

__global__ __launch_bounds__(256) void proj_kernel(
    const void* X0, const void* X1, const void* X2,
    const void* Wq, const void* bq, const void* Wk, const void* bk,
    const void* Wv, const void* bv,
    void* Qw, void* Kw, void* Vw, const int* __restrict__ flags,
    int fx, int fw)
{
    __shared__ __align__(16) short As[64 * 72];
    __shared__ __align__(16) short Bs[128 * 72];
    const int z = blockIdx.z;
    const void* X = (z == 0) ? X0 : ((z == 1) ? X1 : X2);
    const void* W = (z == 0) ? Wq : ((z == 1) ? Wk : Wv);
    const void* B = (z == 0) ? bq : ((z == 1) ? bk : bv);
    void* Y = (z == 0) ? Qw : ((z == 1) ? Kw : Vw);
    const bool xb = fx || flags[0] != 0;
    const bool wb = fw || flags[2] != 0;
    const bool biasbf = flags[2] != 0;
    const bool ybf = (flags[0] != 0) || (z != 0);
    if (xb) { if (wb) proj_body<true , true >(X, W, B, biasbf, Y, ybf, z, blockIdx.x, blockIdx.y, As, Bs);
              else    proj_body<true , false>(X, W, B, biasbf, Y, ybf, z, blockIdx.x, blockIdx.y, As, Bs); }
    else    { if (wb) proj_body<false, true >(X, W, B, biasbf, Y, ybf, z, blockIdx.x, blockIdx.y, As, Bs);
              else    proj_body<false, false>(X, W, B, biasbf, Y, ybf, z, blockIdx.x, blockIdx.y, As, Bs); }
}

// ---------------- Flash attention with distance-aware key bias --------------
// Round-7 structure, widened to QBLK=128 q rows per block (8 waves, 512 thr):
// each thread stages ONE short8 of K and one of V per tile (was two each),
// K/V L2 traffic halves (8 blocks share a head's K/V, was 16), barriers per
// q-row halve. Per-wave MFMA/softmax identical. Grid 8 x 12 x 4 = 384 blocks,
// all resident. LDS: 32 KB KV + 5 KB qe.
template<bool QB, bool EB>
__device__ __forceinline__ void attn_body(
    const void* Qw, const short* __restrict__ Ks, const short* __restrict__ Vs,
    const unsigned char* __restrict__ idxb, const void* __restrict__ emb, void* out,
    unsigned short* Klds, unsigned short* Vtlds, float* qe)
{
    const int qt = blockIdx.x, h = blockIdx.y, b = blockIdx.z;
    const int tid  = threadIdx.x;
    const int wave = tid >> 6;          // 0..7
    const int lane = tid & 63;
    const int l15  = lane & 15;
    const int quad = lane >> 4;

    const float CSC = 0.18033688011112042f;   // 0.125 * log2(e)

    // qe[row][e] = (sum_d Q[b,qrow,h*64+d] * emb[e][d]) * CSC  (flat, 128 rows)
    for (int p = tid; p < QBLK * NUMEMB; p += 512) {
        const int row = p / NUMEMB, e = p - row * NUMEMB;
        const size_t qoff = ((size_t)b * Ssz + qt * QBLK + row) * Dsz + h * DKsz;
        float s = 0.f;
#pragma unroll
        for (int c = 0; c < 8; c++) {
            short8 qv = load8bf<QB>(Qw, qoff + c * 8);
            float8 ef = load8f<EB>(emb, (size_t)e * DKsz + c * 8);
#pragma unroll
            for (int i = 0; i < 8; i++) s += bfbits2f(qv[i]) * ef[i];
        }
        qe[p] = s * CSC;
    }

    // Q fragment (B-operand): col = l15 -> q row, k = quad*8 + j
    short8 qfrag[2];
    {
        const size_t qbase = ((size_t)b * Ssz + qt * QBLK + wave * 16 + l15) * Dsz + h * DKsz;
        qfrag[0] = load8bf<QB>(Qw, qbase + quad * 8);
        qfrag[1] = load8bf<QB>(Qw, qbase + 32 + quad * 8);
    }

    float m_run = -1e30f, l_run = 0.f;
    f32x4 oacc[4];
#pragma unroll
    for (int j = 0; j < 4; j++) oacc[j] = (f32x4)0.0f;

    // staging lane mapping (write side), [64][64] XOR swizzle.
    // r0 spans the full 64-row tile (512 threads x one short8 each).
    // swz(row) = (row&3)|(((row>>3)&1)<<2) -- same layout as rounds 6-9.
    const int r0 = tid >> 3, cc = tid & 7;
    const int swr   = (r0 & 3) | (((r0 >> 3) & 1) << 2);
    const int wroff = r0 * 64 + (cc ^ swr) * 8;

    // frag read offsets (swizzle-matched; verified rounds 5-9)
    const int swk = (l15 & 3) | (((l15 >> 2) & 1) << 2);
    const int vsw = (l15 & 3) | (((l15 >> 3) & 1) << 2);
    int koff[4][2];
#pragma unroll
    for (int jb = 0; jb < 4; jb++) {
        const int krow = (jb & 2) * 16 + (l15 >> 2) * 8 + (jb & 1) * 4 + (l15 & 3);
#pragma unroll
        for (int st = 0; st < 2; st++)
            koff[jb][st] = krow * 64 + ((st * 4 + quad) ^ swk) * 8;
    }
    int voff[2];
#pragma unroll
    for (int st = 0; st < 2; st++) voff[st] = ((st * 4 + quad) ^ vsw) * 8;

    const short* kp = Ks + ((size_t)(b * Hn + h) * Ssz) * DKsz + tid * 8;          // row r0, chunk cc
    const short* vp = Vs + ((size_t)(b * Hn + h) * DKsz + r0) * Ssz + cc * 8;
    const unsigned char* ip = idxb + ((size_t)b * Ssz + qt * QBLK + wave * 16 + l15) * Ssz + quad * 8;
    const int qrow10 = (wave * 16 + l15) * NUMEMB;

    // preload tile 0
    short8 pk = *(const short8*)(kp);
    short8 pv = *(const short8*)(vp);
    u32x2 idA = *(const u32x2*)(ip);
    u32x2 idB = *(const u32x2*)(ip + 32);

    *(short8*)&Klds[wroff]  = pk;
    *(short8*)&Vtlds[wroff] = pv;
    __syncthreads();   // buf0 staged; qe visible

    for (int it = 0; it < 16; ++it) {
        const int cur = (it & 1) * KVBUF;
        const int nxt = cur ^ KVBUF;
        const unsigned int jd[4] = { idA[0], idA[1], idB[0], idB[1] };

        if (it + 1 < 16) {   // issue next-tile loads; land under compute (T14)
            kp += 4096;
            vp += 64;
            ip += 64;
            pk = *(const short8*)(kp);
            pv = *(const short8*)(vp);
            idA = *(const u32x2*)(ip);
            idB = *(const u32x2*)(ip + 32);
        }

        // S^T = K Q^T via MFMA (A = permuted K rows, B = Q)
        f32x4 sf[4];
#pragma unroll
        for (int jb = 0; jb < 4; jb++) sf[jb] = (f32x4)0.0f;
        __builtin_amdgcn_s_setprio(1);
#pragma unroll
        for (int st = 0; st < 2; st++) {
#pragma unroll
            for (int jb = 0; jb < 4; jb++) {
                short8 kf = *(const short8*)&Klds[cur + koff[jb][st]];
                sf[jb] = __builtin_amdgcn_mfma_f32_16x16x32_bf16(kf, qfrag[st], sf[jb], 0, 0, 0);
            }
        }
        __builtin_amdgcn_s_setprio(0);

        // bias via idx regs + pre-scaled qe
        float sv[4][4];
#pragma unroll
        for (int jb = 0; jb < 4; jb++) {
            const unsigned int iw = jd[jb];
#pragma unroll
            for (int r = 0; r < 4; r++)
                sv[jb][r] = fmaf(sf[jb][r], CSC, qe[qrow10 + ((iw >> (8 * r)) & 0xFF)]);
        }

        // online softmax: one q-row per lane (16 in-lane + cross-quad reduce)
        float t0 = fmaxf(fmaxf(sv[0][0], sv[0][1]), fmaxf(sv[0][2], sv[0][3]));
        float t1 = fmaxf(fmaxf(sv[1][0], sv[1][1]), fmaxf(sv[1][2], sv[1][3]));
        float t2 = fmaxf(fmaxf(sv[2][0], sv[2][1]), fmaxf(sv[2][2], sv[2][3]));
        float t3 = fmaxf(fmaxf(sv[3][0], sv[3][1]), fmaxf(sv[3][2], sv[3][3]));
        float vmax = fmaxf(fmaxf(t0, t1), fmaxf(t2, t3));
        vmax = fmaxf(vmax, __shfl_xor(vmax, 16, 64));
        vmax = fmaxf(vmax, __shfl_xor(vmax, 32, 64));

        if (!__all(vmax - m_run <= 8.0f)) {   // defer-max (T13)
            const float mnew = fmaxf(m_run, vmax);
            const float alpha = exp2f(m_run - mnew);
            m_run = mnew;
            l_run *= alpha;
            float aO[4];
#pragma unroll
            for (int r = 0; r < 4; r++)
                aO[r] = __shfl(alpha, (lane & 48) | (quad * 4 + r), 64);
#pragma unroll
            for (int j = 0; j < 4; j++) {
                f32x4 o = oacc[j];
#pragma unroll
                for (int r = 0; r < 4; r++) o[r] *= aO[r];
                oacc[j] = o;
            }
        }

#pragma unroll
        for (int jb = 0; jb < 4; jb++)
#pragma unroll
            for (int r = 0; r < 4; r++)
                sv[jb][r] = exp2f(sv[jb][r] - m_run);

        float s0 = (sv[0][0] + sv[0][1]) + (sv[0][2] + sv[0][3]);
        float s1 = (sv[1][0] + sv[1][1]) + (sv[1][2] + sv[1][3]);
        float s2 = (sv[2][0] + sv[2][1]) + (sv[2][2] + sv[2][3]);
        float s3 = (sv[3][0] + sv[3][1]) + (sv[3][2] + sv[3][3]);
        float psum = (s0 + s1) + (s2 + s3);
        psum += __shfl_xor(psum, 16, 64);
        psum += __shfl_xor(psum, 32, 64);
        l_run += psum;

        // P -> bf16 A-fragments, entirely in-lane (kv = st*32 + quad*8 + j)
        short8 pa[2];
#pragma unroll
        for (int st = 0; st < 2; st++)
#pragma unroll
            for (int j = 0; j < 8; j++)
                pa[st][j] = (short)f2bf_bits(sv[2 * st + (j >> 2)][j & 3]);

        // O += P @ V via MFMA (V pre-transposed: row = d, col = kv)
        __builtin_amdgcn_s_setprio(1);
#pragma unroll
        for (int st = 0; st < 2; st++) {
#pragma unroll
            for (int j = 0; j < 4; j++) {
                short8 vb = *(const short8*)&Vtlds[cur + (j * 16 + l15) * 64 + voff[st]];
                oacc[j] = __builtin_amdgcn_mfma_f32_16x16x32_bf16(pa[st], vb, oacc[j], 0, 0, 0);
            }
        }
        __builtin_amdgcn_s_setprio(0);

        // write next tile into the other LDS buffer (one short8 each)
        if (it + 1 < 16) {
            *(short8*)&Klds[nxt + wroff]  = pk;
            *(short8*)&Vtlds[nxt + wroff] = pv;
        }
        __syncthreads();   // single barrier per KV tile
    }

    // epilogue: redistribute 1/l from row-owner lanes (l15 == quad*4+r)
    const float inv = 1.0f / l_run;
    float invO[4];
#pragma unroll
    for (int r = 0; r < 4; r++)
        invO[r] = __shfl(inv, (lane & 48) | (quad * 4 + r), 64);

#pragma unroll
    for (int r = 0; r < 4; r++) {
        const int m = qt * QBLK + wave * 16 + quad * 4 + r;
#pragma unroll
        for (int j = 0; j < 4; j++) {
            const int n = h * DKsz + j * 16 + l15;
            const float val = oacc[j][r] * invO[r];
            const size_t oidx = ((size_t)b * Ssz + m) * Dsz + n;
            if constexpr (QB) ((__hip_bfloat16*)out)[oidx] = __float2bfloat16(val);
            else              ((float*)out)[oidx] = val;
        }
    }
}

__global__ __launch_bounds__(512) void attn_kernel(
    const void* Qw, const short* __restrict__ Ks, const short* __restrict__ Vs,
    const unsigned char* __restrict__ idxb, const void* __restrict__ emb, void* out,
    const int* __restrict__ flags)
{
    __shared__ __align__(16) unsigned short Klds[2 * KVBUF];
    __shared__ __align__(16) unsigned short Vtlds[2 * KVBUF];
    __shared__ __align__(16) float qe[QBLK * NUMEMB];

    const bool qb = flags[0] != 0, eb = flags[3] != 0;
    if (qb) { if (eb) attn_body<true , true >(Qw, Ks, Vs, idxb, emb, out, Klds, Vtlds, qe);
              else    attn_body<true , false>(Qw, Ks, Vs, idxb, emb, out, Klds, Vtlds, qe); }
    else    { if (eb) attn_body<false, true >(Qw, Ks, Vs, idxb, emb, out, Klds, Vtlds, qe);
              else    attn_body<false, false>(Qw, Ks, Vs, idxb, emb, out, Klds, Vtlds, qe); }
}

extern "C" void kernel_launch(void* const* d_in, const int* in_sizes, int n_in,
                              void* d_out, int out_size, void* d_ws, size_t ws_size,
                              hipStream_t stream) {
    const void* query = d_in[0];
    const void* key   = d_in[1];
    const void* value = d_in[2];
    const void* tpos  = d_in[3];
    const void* Wq    = d_in[4];
    const void* bq    = d_in[5];
    const void* Wk    = d_in[6];
    const void* bk    = d_in[7];
    const void* Wv    = d_in[8];
    const void* bv    = d_in[9];
    const void* emb   = d_in[10];

    int*           flags = (int*)d_ws;
    unsigned char* idxb  = (unsigned char*)d_ws + IDX_OFF;
    void*          Kw    = (char*)d_ws + K_OFF;    // [b][h][s][dk] bf16
    void*          Vw    = (char*)d_ws + V_OFF;    // [b][h][dk][s] bf16
    short*         Wbf   = (short*)((char*)d_ws + WBF_OFF);
    short*         Xbf   = (short*)((char*)d_ws + XBF_OFF);
    void*          Qw    = d_out;   // Q staged in d_out

    const bool tierA = ws_size >= WS_TIER_A;
    const bool tierB = !tierA && ws_size >= WS_TIER_B;

    if (tierA) {
        prep_kernel<<<5472 + 1024, 256, 0, stream>>>(
            query, key, value, Wq, Wk, Wv, tpos, emb,
            flags, Xbf, Wbf, idxb, 5472, 1);
        proj_kernel<<<dim3(64, 6, 3), 256, 0, stream>>>(
            Xbf, Xbf + NXz, Xbf + 2 * NXz,
            Wbf, bq, Wbf + NWz, bk, Wbf + 2 * NWz, bv,
            Qw, Kw, Vw, flags, 1, 1);
    } else if (tierB) {
        prep_kernel<<<864 + 1024, 256, 0, stream>>>(
            query, key, value, Wq, Wk, Wv, tpos, emb,
            flags, Xbf, Wbf, idxb, 864, 0);
        proj_kernel<<<dim3(64, 6, 3), 256, 0, stream>>>(
            query, key, value,
            Wbf, bq, Wbf + NWz, bk, Wbf + 2 * NWz, bv,
            Qw, Kw, Vw, flags, 0, 1);
    } else {
        detect_kernel<<<4, 64, 0, stream>>>(
            (const unsigned int*)query, (const unsigned int*)tpos,
            (const unsigned int*)Wq, (const unsigned int*)emb, flags);
        idx_kernel<<<dim3(16, 16, Bsz), 256, 0, stream>>>(tpos, flags, idxb);
        proj_kernel<<<dim3(64, 6, 3), 256, 0, stream>>>(
            query, key, value, Wq, bq, Wk, bk, Wv, bv,
            Qw, Kw, Vw, flags, 0, 0);
    }

    attn_kernel<<<dim3(Ssz / QBLK, Hn, Bsz), 512, 0, stream>>>(
        Qw, (const short*)Kw, (const short*)Vw, idxb, emb, d_out, flags);
}

// Round 11
// 200.646 us; speedup vs baseline: 1.0348x; 1.0348x over previous
//
#include <hip/hip_runtime.h>
#include <hip/hip_bf16.h>

#define Bsz 4
#define Ssz 1024
#define Dsz 768
#define Hn 12
#define DKsz 64
#define NUMEMB 10

// d_ws layout (bytes)
#define IDX_OFF 64
#define K_OFF   4194368          // IDX_OFF + 4*1024*1024
#define V_OFF   10485824         // K_OFF + 4*1024*768*2
#define WBF_OFF 16777280         // V_OFF + 4*1024*768*2
#define XBF_OFF 20316224         // WBF_OFF + 3*768*768*2
#define WS_TIER_B 20316224ULL    // enough for Wbf
#define WS_TIER_A 39190592ULL    // enough for Wbf + Xbf

#define NXz 3145728              // elems per X tensor (4*1024*768)
#define NWz 589824               // elems per W tensor (768*768)

// attn LDS: double-buffered unpadded [64][64], XOR chunk swizzle
#define KVBUF 4096               // shorts per buffer (64*64)

typedef __attribute__((ext_vector_type(8))) short short8;
typedef __attribute__((ext_vector_type(8))) float float8;
typedef __attribute__((ext_vector_type(4))) float f32x4;
typedef __attribute__((ext_vector_type(4))) unsigned int u32x4;
typedef __attribute__((ext_vector_type(2))) unsigned int u32x2;
typedef __attribute__((ext_vector_type(4))) short s16x4;

__device__ __forceinline__ float bfbits2f(short u) {
    union { unsigned int i; float f; } v;
    v.i = ((unsigned int)(unsigned short)u) << 16;
    return v.f;
}
__device__ __forceinline__ unsigned short f2bf_bits(float f) {
    __hip_bfloat16 h = __float2bfloat16(f);
    return *reinterpret_cast<unsigned short*>(&h);
}

// wave-local dtype vote. Returns 1 = bf16, 0 = f32. Uniform per wave.
__device__ __forceinline__ int dtvote(const unsigned int* p, int n) {
    int cnt = 0;
    for (int i = (threadIdx.x & 63); i < n; i += 64) {
        const unsigned int ex = (p[i] >> 7) & 0xFF;
        cnt += (ex >= 110 && ex <= 145) ? 1 : 0;
    }
#pragma unroll
    for (int off = 1; off < 64; off <<= 1) cnt += __shfl_xor(cnt, off, 64);
    return (2 * cnt > n) ? 1 : 0;
}

// dtype-dispatched loads: idx is an ELEMENT index
template<bool BF16>
__device__ __forceinline__ float loadf(const void* base, size_t idx) {
    if constexpr (BF16) return __bfloat162float(((const __hip_bfloat16*)base)[idx]);
    else return ((const float*)base)[idx];
}
template<bool BF16>
__device__ __forceinline__ short8 load8bf(const void* base, size_t idx) {
    if constexpr (BF16) {
        return *(const short8*)((const short*)base + idx);
    } else {
        float8 f = *(const float8*)((const float*)base + idx);
        short8 r;
#pragma unroll
        for (int i = 0; i < 8; i++) r[i] = (short)f2bf_bits(f[i]);
        return r;
    }
}
template<bool BF16>
__device__ __forceinline__ float8 load8f(const void* base, size_t idx) {
    if constexpr (BF16) {
        short8 s = *(const short8*)((const short*)base + idx);
        float8 f;
#pragma unroll
        for (int i = 0; i < 8; i++) f[i] = bfbits2f(s[i]);
        return f;
    } else {
        return *(const float8*)((const float*)base + idx);
    }
}

// ---------------- idx tile body (shared by idx_kernel and prep_kernel) -----
// Exact fp32 op chain matching numpy; matrix is bitwise symmetric.
template<bool PB>
__device__ __forceinline__ void idx_body(
    const void* pos, unsigned char* __restrict__ idxb, int kt, int qt, int b)
{
    const int t = threadIdx.x;
    const int r = t >> 2, cc = t & 3;
    const int q = qt * 64 + r;
    const float qx = loadf<PB>(pos, ((size_t)b * Ssz + q) * 2);
    const float qy = loadf<PB>(pos, ((size_t)b * Ssz + q) * 2 + 1);
    const float MAXD = 141421.35623730951f;  // fp32(100000*sqrt(2))
    const int k0 = kt * 64 + cc * 16;
    unsigned int w[4];
#pragma unroll
    for (int g = 0; g < 4; g++) {
        unsigned int acc = 0;
#pragma unroll
        for (int u = 0; u < 4; u++) {
            const int k = k0 + g * 4 + u;
            const float kx = loadf<PB>(pos, ((size_t)b * Ssz + k) * 2);
            const float ky = loadf<PB>(pos, ((size_t)b * Ssz + k) * 2 + 1);
            const float dx = __fsub_rn(qx, kx);
            const float dy = __fsub_rn(qy, ky);
            const float ss = __fadd_rn(__fmul_rn(dx, dx), __fmul_rn(dy, dy));
            const float dist = __fdiv_rn(sqrtf(ss), MAXD);
            const float d9 = __fmul_rn(dist, 9.0f);
            int idx = (int)rintf(d9);
            idx = idx < 0 ? 0 : (idx > NUMEMB - 1 ? NUMEMB - 1 : idx);
            acc |= ((unsigned int)idx) << (8 * u);
        }
        w[g] = acc;
    }
    u32x4 v; v[0] = w[0]; v[1] = w[1]; v[2] = w[2]; v[3] = w[3];
    *(u32x4*)(idxb + ((size_t)(b * Ssz + q)) * Ssz + k0) = v;
}

// ---------------- dtype detector (tierC only) ------------------------------
__global__ __launch_bounds__(64) void detect_kernel(
    const unsigned int* __restrict__ q, const unsigned int* __restrict__ p,
    const unsigned int* __restrict__ w, const unsigned int* __restrict__ e,
    int* __restrict__ flags)
{
    const int which = blockIdx.x;
    const unsigned int* ptr = (which == 0) ? q : ((which == 1) ? p : ((which == 2) ? w : e));
    const int n = (which == 3) ? 320 : ((which == 1) ? 4096 : 1024);
    const int f = dtvote(ptr, n);
    if (threadIdx.x == 0) flags[which] = f;
}

__global__ __launch_bounds__(256) void idx_kernel(
    const void* pos, const int* __restrict__ flags, unsigned char* __restrict__ idxb)
{
    if (flags[1] != 0) idx_body<true >(pos, idxb, blockIdx.x, blockIdx.y, blockIdx.z);
    else               idx_body<false>(pos, idxb, blockIdx.x, blockIdx.y, blockIdx.z);
}

// ---------------- prep: fused conv + idx + flag duty (tierA/B) -------------
// Blocks [0, nconv): bf16 canonicalization of X/W (local dtype votes,
// blocks 0-3 also publish flags for downstream proj/attn).
// Blocks [nconv, nconv+1024): idx tiles (local tpos vote).
__global__ __launch_bounds__(256) void prep_kernel(
    const void* __restrict__ X0, const void* __restrict__ X1, const void* __restrict__ X2,
    const void* __restrict__ W0, const void* __restrict__ W1, const void* __restrict__ W2,
    const void* __restrict__ tpos, const void* __restrict__ emb,
    int* __restrict__ flags, short* __restrict__ Xbf, short* __restrict__ Wbf,
    unsigned char* __restrict__ idxb, int nconv, int doX)
{
    if ((int)blockIdx.x >= nconv) {
        const int i = blockIdx.x - nconv;          // 0..1023
        const int kt = i & 15, qt = (i >> 4) & 15, b = i >> 8;
        const int pb = dtvote((const unsigned int*)tpos, 1024);
        if (pb) idx_body<true >(tpos, idxb, kt, qt, b);
        else    idx_body<false>(tpos, idxb, kt, qt, b);
        return;
    }

    // flag duty for downstream kernels (proj/attn read flags)
    if (blockIdx.x == 1) {
        const int f = dtvote((const unsigned int*)tpos, 1024);
        if (threadIdx.x == 0) flags[1] = f;
    } else if (blockIdx.x == 3) {
        const int f = dtvote((const unsigned int*)emb, 320);
        if (threadIdx.x == 0) flags[3] = f;
    }
    const bool xb = dtvote((const unsigned int*)X0, 256) != 0;
    const bool wb = dtvote((const unsigned int*)W0, 256) != 0;
    if (blockIdx.x == 0 && threadIdx.x == 0) { flags[0] = xb ? 1 : 0; flags[2] = wb ? 1 : 0; }

    const long t = (long)blockIdx.x * 256 + threadIdx.x;
    if (doX) {
        const long i8 = t * 8;
        if (i8 < (long)3 * NXz) {
            const int z = (int)(i8 / NXz);
            const long off = i8 - (long)z * NXz;
            const void* X = (z == 0) ? X0 : ((z == 1) ? X1 : X2);
            short8 v = xb ? load8bf<true>(X, off) : load8bf<false>(X, off);
            *(short8*)(Xbf + i8) = v;
        } else {
            const long j = i8 - (long)3 * NXz;
            const int z = (int)(j / NWz);
            const long off = j - (long)z * NWz;
            const void* W = (z == 0) ? W0 : ((z == 1) ? W1 : W2);
            short8 v = wb ? load8bf<true>(W, off) : load8bf<false>(W, off);
            *(short8*)(Wbf + j) = v;
        }
    } else {
        const long j = t * 8;
        const int z = (int)(j / NWz);
        const long off = j - (long)z * NWz;
        const void* W = (z == 0) ? W0 : ((z == 1) ? W1 : W2);
        short8 v = wb ? load8bf<true>(W, off) : load8bf<false>(W, off);
        *(short8*)(Wbf + j) = v;
    }
}

// ---------------- Projection GEMM: Y = X @ W^T + b (reg-staged, 64x128) ----
// zmode: 0 = Q plain [m][768]; 1 = K [b][h][s][dk] bf16; 2 = V^T [b][h][dk][s] bf16.
template<bool XB, bool WB>
__device__ __forceinline__ void proj_body(
    const void* X, const void* W, const void* bias, bool biasbf, void* Y, bool ybf,
    int zmode, int bx, int by, short* As, short* Bs)
{
    const int tid  = threadIdx.x;
    const int wave = tid >> 6;
    const int lane = tid & 63;
    const int l15  = lane & 15;
    const int quad = lane >> 4;
    const int wm = wave & 1;
    const int wn = wave >> 1;
    const int m0 = bx * 64;
    const int n0 = by * 128;

    f32x4 acc[2][4];
#pragma unroll
    for (int i = 0; i < 2; i++)
#pragma unroll
        for (int j = 0; j < 4; j++) acc[i][j] = (f32x4)0.0f;

    const int r0 = tid >> 3;     // staging row 0..31
    const int cc = tid & 7;      // staging col-chunk (8 elems)

    short8 pa0 = load8bf<XB>(X, (size_t)(m0 + r0)      * Dsz + cc * 8);
    short8 pa1 = load8bf<XB>(X, (size_t)(m0 + 32 + r0) * Dsz + cc * 8);
    short8 pb0 = load8bf<WB>(W, (size_t)(n0 + r0)      * Dsz + cc * 8);
    short8 pb1 = load8bf<WB>(W, (size_t)(n0 + 32 + r0) * Dsz + cc * 8);
    short8 pb2 = load8bf<WB>(W, (size_t)(n0 + 64 + r0) * Dsz + cc * 8);
    short8 pb3 = load8bf<WB>(W, (size_t)(n0 + 96 + r0) * Dsz + cc * 8);

    for (int kk = 0; kk < Dsz; kk += 64) {
        __syncthreads();
        *(short8*)&As[(r0)      * 72 + cc * 8] = pa0;
        *(short8*)&As[(32 + r0) * 72 + cc * 8] = pa1;
        *(short8*)&Bs[(r0)      * 72 + cc * 8] = pb0;
        *(short8*)&Bs[(32 + r0) * 72 + cc * 8] = pb1;
        *(short8*)&Bs[(64 + r0) * 72 + cc * 8] = pb2;
        *(short8*)&Bs[(96 + r0) * 72 + cc * 8] = pb3;
        __syncthreads();

        if (kk + 64 < Dsz) {
            const int k2 = kk + 64 + cc * 8;
            pa0 = load8bf<XB>(X, (size_t)(m0 + r0)      * Dsz + k2);
            pa1 = load8bf<XB>(X, (size_t)(m0 + 32 + r0) * Dsz + k2);
            pb0 = load8bf<WB>(W, (size_t)(n0 + r0)      * Dsz + k2);
            pb1 = load8bf<WB>(W, (size_t)(n0 + 32 + r0) * Dsz + k2);
            pb2 = load8bf<WB>(W, (size_t)(n0 + 64 + r0) * Dsz + k2);
            pb3 = load8bf<WB>(W, (size_t)(n0 + 96 + r0) * Dsz + k2);
        }

#pragma unroll
        for (int st = 0; st < 2; st++) {
            short8 af[2], bf[4];
#pragma unroll
            for (int i = 0; i < 2; i++)
                af[i] = *(const short8*)&As[(wm * 32 + i * 16 + l15) * 72 + st * 32 + quad * 8];
#pragma unroll
            for (int j = 0; j < 4; j++)
                bf[j] = *(const short8*)&Bs[(wn * 64 + j * 16 + l15) * 72 + st * 32 + quad * 8];
#pragma unroll
            for (int i = 0; i < 2; i++)
#pragma unroll
                for (int j = 0; j < 4; j++)
                    acc[i][j] = __builtin_amdgcn_mfma_f32_16x16x32_bf16(af[i], bf[j], acc[i][j], 0, 0, 0);
        }
    }

#pragma unroll
    for (int j = 0; j < 4; j++) {
        const int n = n0 + wn * 64 + j * 16 + l15;
        const float bv_ = biasbf ? loadf<true>(bias, n) : loadf<false>(bias, n);
        const int hh = n >> 6, dk = n & 63;
#pragma unroll
        for (int i = 0; i < 2; i++) {
            const int ms = m0 + wm * 32 + i * 16 + quad * 4;   // 4 consecutive rows
            const int bb = ms >> 10;
            const int s0 = ms & 1023;
            if (zmode == 2) {
                s16x4 pkv;
#pragma unroll
                for (int r = 0; r < 4; r++) pkv[r] = (short)f2bf_bits(acc[i][j][r] + bv_);
                *(s16x4*)((short*)Y + (((size_t)bb * Hn + hh) * DKsz + dk) * Ssz + s0) = pkv;
            } else if (zmode == 1) {
#pragma unroll
                for (int r = 0; r < 4; r++)
                    ((__hip_bfloat16*)Y)[(((size_t)bb * Hn + hh) * Ssz + (s0 + r)) * DKsz + dk] =
                        __float2bfloat16(acc[i][j][r] + bv_);
            } else {
#pragma unroll
                for (int r = 0; r < 4; r++) {
                    const float val = acc[i][j][r] + bv_;
                    const size_t oi = (size_t)(ms + r) * Dsz + n;
                    if (ybf) ((__hip_bfloat16*)Y)[oi] = __float2bfloat16(val);
                    else     ((float*)Y)[oi] = val;
                }
            }
        }
    }
}

__global__ __launch_bounds__(256) void proj_kernel(
    const void* X0, const void* X1, const void* X2,
    const void* Wq, const void* bq, const void* Wk, const void* bk,
    const void* Wv, const void* bv,
    void* Qw, void* Kw, void* Vw, const int* __restrict__ flags,
    int fx, int fw)
{
    __shared__ __align__(16) short As[64 * 72];
    __shared__ __align__(16) short Bs[128 * 72];
    const int z = blockIdx.z;
    const void* X = (z == 0) ? X0 : ((z == 1) ? X1 : X2);
    const void* W = (z == 0) ? Wq : ((z == 1) ? Wk : Wv);
    const void* B = (z == 0) ? bq : ((z == 1) ? bk : bv);
    void* Y = (z == 0) ? Qw : ((z == 1) ? Kw : Vw);
    const bool xb = fx || flags[0] != 0;
    const bool wb = fw || flags[2] != 0;
    const bool biasbf = flags[2] != 0;
    const bool ybf = (flags[0] != 0) || (z != 0);
    if (xb) { if (wb) proj_body<true , true >(X, W, B, biasbf, Y, ybf, z, blockIdx.x, blockIdx.y, As, Bs);
              else    proj_body<true , false>(X, W, B, biasbf, Y, ybf, z, blockIdx.x, blockIdx.y, As, Bs); }
    else    { if (wb) proj_body<false, true >(X, W, B, biasbf, Y, ybf, z, blockIdx.x, blockIdx.y, As, Bs);
              else    proj_body<false, false>(X, W, B, biasbf, Y, ybf, z, blockIdx.x, blockIdx.y, As, Bs); }
}

// ---------------- Flash attention with distance-aware key bias --------------
// Round-9 structure (proven 201.4 total): QBLK=64, 4 waves, double-buffered
// K/V, loads at iter top, write-next after PV, one barrier per tile,
// [64][64] XOR-swizzled LDS, __shfl_xor cross-quad reductions.
// New: XCD-aware block swizzle (T1) — each XCD owns 6 complete (b,h) groups
// (all 16 qt tiles), so a group's K/V + idx slice lives in ONE L2.
// Bijective: 768 blocks % 8 XCDs == 0.
template<bool QB, bool EB>
__device__ __forceinline__ void attn_body(
    const void* Qw, const short* __restrict__ Ks, const short* __restrict__ Vs,
    const unsigned char* __restrict__ idxb, const void* __restrict__ emb, void* out,
    unsigned short* Klds, unsigned short* Vtlds, float* qe)
{
    // XCD swizzle: linear dispatch id -> (xcd, slot) -> work id
    const int linear = blockIdx.x + 16 * (blockIdx.y + Hn * blockIdx.z);  // 0..767
    const int work = (linear & 7) * 96 + (linear >> 3);                   // bijective
    const int qt = work & 15;
    const int bh = work >> 4;            // 0..47
    const int h = bh % Hn;
    const int b = bh / Hn;

    const int tid  = threadIdx.x;
    const int wave = tid >> 6;
    const int lane = tid & 63;
    const int l15  = lane & 15;
    const int quad = lane >> 4;

    const float CSC = 0.18033688011112042f;   // 0.125 * log2(e)

    // qe[row][e] = (sum_d Q[b,qrow,h*64+d] * emb[e][d]) * CSC  (flat)
    for (int p = tid; p < 64 * NUMEMB; p += 256) {
        const int row = p / NUMEMB, e = p - row * NUMEMB;
        const size_t qoff = ((size_t)b * Ssz + qt * 64 + row) * Dsz + h * DKsz;
        float s = 0.f;
#pragma unroll
        for (int c = 0; c < 8; c++) {
            short8 qv = load8bf<QB>(Qw, qoff + c * 8);
            float8 ef = load8f<EB>(emb, (size_t)e * DKsz + c * 8);
#pragma unroll
            for (int i = 0; i < 8; i++) s += bfbits2f(qv[i]) * ef[i];
        }
        qe[p] = s * CSC;
    }

    // Q fragment (B-operand): col = l15 -> q row, k = quad*8 + j
    short8 qfrag[2];
    {
        const size_t qbase = ((size_t)b * Ssz + qt * 64 + wave * 16 + l15) * Dsz + h * DKsz;
        qfrag[0] = load8bf<QB>(Qw, qbase + quad * 8);
        qfrag[1] = load8bf<QB>(Qw, qbase + 32 + quad * 8);
    }

    float m_run = -1e30f, l_run = 0.f;
    f32x4 oacc[4];
#pragma unroll
    for (int j = 0; j < 4; j++) oacc[j] = (f32x4)0.0f;

    // staging lane mapping (write side), [64][64] XOR swizzle
    const int r0 = tid >> 3, cc = tid & 7;
    const int swr   = (r0 & 3) | (((r0 >> 3) & 1) << 2);
    const int wroff = r0 * 64 + (cc ^ swr) * 8;          // rows r0 and r0+32 share swr

    // frag read offsets (swizzle-matched; verified rounds 5-9)
    const int swk = (l15 & 3) | (((l15 >> 2) & 1) << 2);
    const int vsw = (l15 & 3) | (((l15 >> 3) & 1) << 2);
    int koff[4][2];
#pragma unroll
    for (int jb = 0; jb < 4; jb++) {
        const int krow = (jb & 2) * 16 + (l15 >> 2) * 8 + (jb & 1) * 4 + (l15 & 3);
#pragma unroll
        for (int st = 0; st < 2; st++)
            koff[jb][st] = krow * 64 + ((st * 4 + quad) ^ swk) * 8;
    }
    int voff[2];
#pragma unroll
    for (int st = 0; st < 2; st++) voff[st] = ((st * 4 + quad) ^ vsw) * 8;

    const short* kp = Ks + ((size_t)(b * Hn + h) * Ssz) * DKsz + tid * 8;
    const short* vp = Vs + ((size_t)(b * Hn + h) * DKsz + r0) * Ssz + cc * 8;
    const unsigned char* ip = idxb + ((size_t)b * Ssz + qt * 64 + wave * 16 + l15) * Ssz + quad * 8;
    const int qrow10 = (wave * 16 + l15) * NUMEMB;

    // preload tile 0
    short8 pk0 = *(const short8*)(kp);
    short8 pk1 = *(const short8*)(kp + 2048);
    short8 pv0 = *(const short8*)(vp);
    short8 pv1 = *(const short8*)(vp + 32 * Ssz);
    u32x2 idA = *(const u32x2*)(ip);
    u32x2 idB = *(const u32x2*)(ip + 32);

    *(short8*)&Klds[wroff]            = pk0;
    *(short8*)&Klds[32 * 64 + wroff]  = pk1;
    *(short8*)&Vtlds[wroff]           = pv0;
    *(short8*)&Vtlds[32 * 64 + wroff] = pv1;
    __syncthreads();   // buf0 staged; qe visible

    for (int it = 0; it < 16; ++it) {
        const int cur = (it & 1) * KVBUF;
        const int nxt = cur ^ KVBUF;
        const unsigned int jd[4] = { idA[0], idA[1], idB[0], idB[1] };

        if (it + 1 < 16) {   // issue next-tile loads; land under compute (T14)
            kp += 4096;
            vp += 64;
            ip += 64;
            pk0 = *(const short8*)(kp);
            pk1 = *(const short8*)(kp + 2048);
            pv0 = *(const short8*)(vp);
            pv1 = *(const short8*)(vp + 32 * Ssz);
            idA = *(const u32x2*)(ip);
            idB = *(const u32x2*)(ip + 32);
        }

        // S^T = K Q^T via MFMA (A = permuted K rows, B = Q)
        f32x4 sf[4];
#pragma unroll
        for (int jb = 0; jb < 4; jb++) sf[jb] = (f32x4)0.0f;
        __builtin_amdgcn_s_setprio(1);
#pragma unroll
        for (int st = 0; st < 2; st++) {
#pragma unroll
            for (int jb = 0; jb < 4; jb++) {
                short8 kf = *(const short8*)&Klds[cur + koff[jb][st]];
                sf[jb] = __builtin_amdgcn_mfma_f32_16x16x32_bf16(kf, qfrag[st], sf[jb], 0, 0, 0);
            }
        }
        __builtin_amdgcn_s_setprio(0);

        // bias via idx regs + pre-scaled qe
        float sv[4][4];
#pragma unroll
        for (int jb = 0; jb < 4; jb++) {
            const unsigned int iw = jd[jb];
#pragma unroll
            for (int r = 0; r < 4; r++)
                sv[jb][r] = fmaf(sf[jb][r], CSC, qe[qrow10 + ((iw >> (8 * r)) & 0xFF)]);
        }

        // online softmax: one q-row per lane (16 in-lane + cross-quad reduce)
        float t0 = fmaxf(fmaxf(sv[0][0], sv[0][1]), fmaxf(sv[0][2], sv[0][3]));
        float t1 = fmaxf(fmaxf(sv[1][0], sv[1][1]), fmaxf(sv[1][2], sv[1][3]));
        float t2 = fmaxf(fmaxf(sv[2][0], sv[2][1]), fmaxf(sv[2][2], sv[2][3]));
        float t3 = fmaxf(fmaxf(sv[3][0], sv[3][1]), fmaxf(sv[3][2], sv[3][3]));
        float vmax = fmaxf(fmaxf(t0, t1), fmaxf(t2, t3));
        vmax = fmaxf(vmax, __shfl_xor(vmax, 16, 64));
        vmax = fmaxf(vmax, __shfl_xor(vmax, 32, 64));

        if (!__all(vmax - m_run <= 8.0f)) {   // defer-max (T13)
            const float mnew = fmaxf(m_run, vmax);
            const float alpha = exp2f(m_run - mnew);
            m_run = mnew;
            l_run *= alpha;
            float aO[4];
#pragma unroll
            for (int r = 0; r < 4; r++)
                aO[r] = __shfl(alpha, (lane & 48) | (quad * 4 + r), 64);
#pragma unroll
            for (int j = 0; j < 4; j++) {
                f32x4 o = oacc[j];
#pragma unroll
                for (int r = 0; r < 4; r++) o[r] *= aO[r];
                oacc[j] = o;
            }
        }

#pragma unroll
        for (int jb = 0; jb < 4; jb++)
#pragma unroll
            for (int r = 0; r < 4; r++)
                sv[jb][r] = exp2f(sv[jb][r] - m_run);

        float s0 = (sv[0][0] + sv[0][1]) + (sv[0][2] + sv[0][3]);
        float s1 = (sv[1][0] + sv[1][1]) + (sv[1][2] + sv[1][3]);
        float s2 = (sv[2][0] + sv[2][1]) + (sv[2][2] + sv[2][3]);
        float s3 = (sv[3][0] + sv[3][1]) + (sv[3][2] + sv[3][3]);
        float psum = (s0 + s1) + (s2 + s3);
        psum += __shfl_xor(psum, 16, 64);
        psum += __shfl_xor(psum, 32, 64);
        l_run += psum;

        // P -> bf16 A-fragments, entirely in-lane (kv = st*32 + quad*8 + j)
        short8 pa[2];
#pragma unroll
        for (int st = 0; st < 2; st++)
#pragma unroll
            for (int j = 0; j < 8; j++)
                pa[st][j] = (short)f2bf_bits(sv[2 * st + (j >> 2)][j & 3]);

        // O += P @ V via MFMA (V pre-transposed: row = d, col = kv)
        __builtin_amdgcn_s_setprio(1);
#pragma unroll
        for (int st = 0; st < 2; st++) {
#pragma unroll
            for (int j = 0; j < 4; j++) {
                short8 vb = *(const short8*)&Vtlds[cur + (j * 16 + l15) * 64 + voff[st]];
                oacc[j] = __builtin_amdgcn_mfma_f32_16x16x32_bf16(pa[st], vb, oacc[j], 0, 0, 0);
            }
        }
        __builtin_amdgcn_s_setprio(0);

        // write next tile into the other LDS buffer
        if (it + 1 < 16) {
            *(short8*)&Klds[nxt + wroff]            = pk0;
            *(short8*)&Klds[nxt + 32 * 64 + wroff]  = pk1;
            *(short8*)&Vtlds[nxt + wroff]           = pv0;
            *(short8*)&Vtlds[nxt + 32 * 64 + wroff] = pv1;
        }
        __syncthreads();   // single barrier per KV tile
    }

    // epilogue: redistribute 1/l from row-owner lanes (l15 == quad*4+r)
    const float inv = 1.0f / l_run;
    float invO[4];
#pragma unroll
    for (int r = 0; r < 4; r++)
        invO[r] = __shfl(inv, (lane & 48) | (quad * 4 + r), 64);

#pragma unroll
    for (int r = 0; r < 4; r++) {
        const int m = qt * 64 + wave * 16 + quad * 4 + r;
#pragma unroll
        for (int j = 0; j < 4; j++) {
            const int n = h * DKsz + j * 16 + l15;
            const float val = oacc[j][r] * invO[r];
            const size_t oidx = ((size_t)b * Ssz + m) * Dsz + n;
            if constexpr (QB) ((__hip_bfloat16*)out)[oidx] = __float2bfloat16(val);
            else              ((float*)out)[oidx] = val;
        }
    }
}

__global__ __launch_bounds__(256) void attn_kernel(
    const void* Qw, const short* __restrict__ Ks, const short* __restrict__ Vs,
    const unsigned char* __restrict__ idxb, const void* __restrict__ emb, void* out,
    const int* __restrict__ flags)
{
    __shared__ __align__(16) unsigned short Klds[2 * KVBUF];
    __shared__ __align__(16) unsigned short Vtlds[2 * KVBUF];
    __shared__ __align__(16) float qe[64 * NUMEMB];

    const bool qb = flags[0] != 0, eb = flags[3] != 0;
    if (qb) { if (eb) attn_body<true , true >(Qw, Ks, Vs, idxb, emb, out, Klds, Vtlds, qe);
              else    attn_body<true , false>(Qw, Ks, Vs, idxb, emb, out, Klds, Vtlds, qe); }
    else    { if (eb) attn_body<false, true >(Qw, Ks, Vs, idxb, emb, out, Klds, Vtlds, qe);
              else    attn_body<false, false>(Qw, Ks, Vs, idxb, emb, out, Klds, Vtlds, qe); }
}

extern "C" void kernel_launch(void* const* d_in, const int* in_sizes, int n_in,
                              void* d_out, int out_size, void* d_ws, size_t ws_size,
                              hipStream_t stream) {
    const void* query = d_in[0];
    const void* key   = d_in[1];
    const void* value = d_in[2];
    const void* tpos  = d_in[3];
    const void* Wq    = d_in[4];
    const void* bq    = d_in[5];
    const void* Wk    = d_in[6];
    const void* bk    = d_in[7];
    const void* Wv    = d_in[8];
    const void* bv    = d_in[9];
    const void* emb   = d_in[10];

    int*           flags = (int*)d_ws;
    unsigned char* idxb  = (unsigned char*)d_ws + IDX_OFF;
    void*          Kw    = (char*)d_ws + K_OFF;    // [b][h][s][dk] bf16
    void*          Vw    = (char*)d_ws + V_OFF;    // [b][h][dk][s] bf16
    short*         Wbf   = (short*)((char*)d_ws + WBF_OFF);
    short*         Xbf   = (short*)((char*)d_ws + XBF_OFF);
    void*          Qw    = d_out;   // Q staged in d_out

    const bool tierA = ws_size >= WS_TIER_A;
    const bool tierB = !tierA && ws_size >= WS_TIER_B;

    if (tierA) {
        prep_kernel<<<5472 + 1024, 256, 0, stream>>>(
            query, key, value, Wq, Wk, Wv, tpos, emb,
            flags, Xbf, Wbf, idxb, 5472, 1);
        proj_kernel<<<dim3(64, 6, 3), 256, 0, stream>>>(
            Xbf, Xbf + NXz, Xbf + 2 * NXz,
            Wbf, bq, Wbf + NWz, bk, Wbf + 2 * NWz, bv,
            Qw, Kw, Vw, flags, 1, 1);
    } else if (tierB) {
        prep_kernel<<<864 + 1024, 256, 0, stream>>>(
            query, key, value, Wq, Wk, Wv, tpos, emb,
            flags, Xbf, Wbf, idxb, 864, 0);
        proj_kernel<<<dim3(64, 6, 3), 256, 0, stream>>>(
            query, key, value,
            Wbf, bq, Wbf + NWz, bk, Wbf + 2 * NWz, bv,
            Qw, Kw, Vw, flags, 0, 1);
    } else {
        detect_kernel<<<4, 64, 0, stream>>>(
            (const unsigned int*)query, (const unsigned int*)tpos,
            (const unsigned int*)Wq, (const unsigned int*)emb, flags);
        idx_kernel<<<dim3(16, 16, Bsz), 256, 0, stream>>>(tpos, flags, idxb);
        proj_kernel<<<dim3(64, 6, 3), 256, 0, stream>>>(
            query, key, value, Wq, bq, Wk, bk, Wv, bv,
            Qw, Kw, Vw, flags, 0, 0);
    }

    attn_kernel<<<dim3(16, Hn, Bsz), 256, 0, stream>>>(
        Qw, (const short*)Kw, (const short*)Vw, idxb, emb, d_out, flags);
}